// Round 1
// baseline (3232.861 us; speedup 1.0000x reference)
//
#include <hip/hip_runtime.h>
#include <hip/hip_bf16.h>

// EdgeGNN layer: linear1(relu) -> SpMM scatter -> linear2(relu) -> GRUCell
// E=200000, NNZ=1600000, EF=16, M=128. bf16 MFMA for GEMMs, f32 atomics for SpMM.

typedef __attribute__((ext_vector_type(4))) float f32x4;
typedef __attribute__((ext_vector_type(8))) short s16x8;

#define MDIM 128
#define EFDIM 16
#define K1PAD 160   // 144 padded to 5*32

__device__ __forceinline__ ushort f2bf(float f) {
  union { float f; unsigned u; } v; v.f = f;
  unsigned u = v.u;
  unsigned r = (u + 0x7fffu + ((u >> 16) & 1u)) >> 16;  // RNE
  return (ushort)r;
}
__device__ __forceinline__ float bf2f(ushort h) {
  union { unsigned u; float f; } v; v.u = ((unsigned)h) << 16; return v.f;
}
__device__ __forceinline__ s16x8 cvt8(f32x4 a, f32x4 b) {
  s16x8 o;
  o[0] = (short)f2bf(a[0]); o[1] = (short)f2bf(a[1]);
  o[2] = (short)f2bf(a[2]); o[3] = (short)f2bf(a[3]);
  o[4] = (short)f2bf(b[0]); o[5] = (short)f2bf(b[1]);
  o[6] = (short)f2bf(b[2]); o[7] = (short)f2bf(b[3]);
  return o;
}
__device__ __forceinline__ f32x4 mfma16(s16x8 a, s16x8 b, f32x4 c) {
  return __builtin_amdgcn_mfma_f32_16x16x32_bf16(a, b, c, 0, 0, 0);
}
__device__ __forceinline__ float sigmoidf_(float x) { return 1.f / (1.f + __expf(-x)); }

// ---------------- prep: bf16 weight conversion ----------------
// W1b [128][160] (k>=144 zero), W2b [128][128], Wihb [384][128], Whhb [384][128]
__global__ __launch_bounds__(256) void prep_kernel(
    const float* __restrict__ W1, const float* __restrict__ W2,
    const float* __restrict__ Wih, const float* __restrict__ Whh,
    ushort* __restrict__ W1b, ushort* __restrict__ W2b,
    ushort* __restrict__ Wihb, ushort* __restrict__ Whhb) {
  int idx = blockIdx.x * 256 + threadIdx.x;
  if (idx < 128 * K1PAD) {
    int n = idx / K1PAD, k = idx % K1PAD;
    W1b[idx] = (k < 144) ? f2bf(W1[n * 144 + k]) : (ushort)0;
    return;
  }
  int i2 = idx - 128 * K1PAD;
  if (i2 < 128 * 128) { W2b[i2] = f2bf(W2[i2]); return; }
  int i3 = i2 - 128 * 128;
  if (i3 < 384 * 128) { Wihb[i3] = f2bf(Wih[i3]); return; }
  int i4 = i3 - 384 * 128;
  if (i4 < 384 * 128) { Whhb[i4] = f2bf(Whh[i4]); return; }
}

// ---------------- K1: msg1 = relu(concat(mo,ef) @ W1^T + b1), bf16 out ----------------
// block = 256 threads = 4 waves; tile = 64 rows x 128 cols; wave w owns rows w*16..w*16+15.
__global__ __launch_bounds__(256) void linear1_kernel(
    const float* __restrict__ mo, const float* __restrict__ ef,
    const ushort* __restrict__ W1b, const float* __restrict__ b1,
    ushort* __restrict__ msg1b) {
  const int tid = threadIdx.x;
  const int wave = tid >> 6, lane = tid & 63;
  const int r = lane & 15, kg = lane >> 4;
  const int row0 = blockIdx.x * 64 + wave * 16;
  const int arow = row0 + r;
  f32x4 acc[8] = {};
#pragma unroll
  for (int step = 0; step < 5; ++step) {
    const int k0 = step * 32 + kg * 8;
    s16x8 a;
    if (k0 < 128) {
      f32x4 f1 = *(const f32x4*)(mo + (size_t)arow * MDIM + k0);
      f32x4 f2 = *(const f32x4*)(mo + (size_t)arow * MDIM + k0 + 4);
      a = cvt8(f1, f2);
    } else if (k0 < 144) {
      f32x4 f1 = *(const f32x4*)(ef + (size_t)arow * EFDIM + (k0 - 128));
      f32x4 f2 = *(const f32x4*)(ef + (size_t)arow * EFDIM + (k0 - 128) + 4);
      a = cvt8(f1, f2);
    } else {
      a = (s16x8){0, 0, 0, 0, 0, 0, 0, 0};
    }
#pragma unroll
    for (int f = 0; f < 8; ++f) {
      const int col = f * 16 + r;
      s16x8 b = *(const s16x8*)(W1b + col * K1PAD + k0);
      acc[f] = mfma16(a, b, acc[f]);
    }
  }
#pragma unroll
  for (int f = 0; f < 8; ++f) {
    const int col = f * 16 + r;
    const float bias = b1[col];
#pragma unroll
    for (int j = 0; j < 4; ++j) {
      const int orow = row0 + kg * 4 + j;  // C/D layout: col=lane&15, row=(lane>>4)*4+j
      float v = acc[f][j] + bias;
      v = v > 0.f ? v : 0.f;
      msg1b[(size_t)orow * MDIM + col] = f2bf(v);
    }
  }
}

// ---------------- K3: SpMM scatter with f32 atomics ----------------
// 32 lanes per nnz; lane g handles columns 4g..4g+3.
__global__ __launch_bounds__(256) void spmm_kernel(
    const int* __restrict__ rows, const int* __restrict__ cols,
    const float* __restrict__ vals, const ushort* __restrict__ msg1b,
    float* __restrict__ msg2, int nnz) {
  const int g = blockIdx.x * 256 + threadIdx.x;
  const int i = g >> 5;
  if (i >= nnz) return;
  const int lane = g & 31;
  const int row = rows[i], col = cols[i];
  const float val = vals[i];
  const ushort4 m = *(const ushort4*)(msg1b + (size_t)col * MDIM + lane * 4);
  float* dst = msg2 + (size_t)row * MDIM + lane * 4;
  atomicAdd(dst + 0, bf2f(m.x) * val);
  atomicAdd(dst + 1, bf2f(m.y) * val);
  atomicAdd(dst + 2, bf2f(m.z) * val);
  atomicAdd(dst + 3, bf2f(m.w) * val);
}

// ---------------- K4: fused linear2(relu) + GRUCell ----------------
// block = 256 threads = 4 waves; tile = 64 rows. Stage1: msg3 -> LDS (bf16, +8 pad).
// Stage2: 3 chunks (r,z,n) of gi/gh; r,z kept in registers.
__global__ __launch_bounds__(256) void gru_kernel(
    const float* __restrict__ msg2, const float* __restrict__ mo,
    const ushort* __restrict__ W2b, const float* __restrict__ b2,
    const ushort* __restrict__ Wihb, const ushort* __restrict__ Whhb,
    const float* __restrict__ bih, const float* __restrict__ bhh,
    float* __restrict__ out) {
  __shared__ ushort msg3b[64][MDIM + 8];
  __shared__ ushort mob[64][MDIM + 8];
  const int tid = threadIdx.x;
  const int wave = tid >> 6, lane = tid & 63;
  const int r = lane & 15, kg = lane >> 4;
  const int row0 = blockIdx.x * 64;
  const int wrow = row0 + wave * 16;

  // cooperative load of message_old tile -> bf16 LDS
#pragma unroll
  for (int it = 0; it < 8; ++it) {
    const int idx = it * 256 + tid;           // 64*32 = 2048 float4 loads
    const int rr = idx >> 5, c4 = (idx & 31) * 4;
    f32x4 v = *(const f32x4*)(mo + (size_t)(row0 + rr) * MDIM + c4);
    ushort4 u;
    u.x = f2bf(v[0]); u.y = f2bf(v[1]); u.z = f2bf(v[2]); u.w = f2bf(v[3]);
    *(ushort4*)&mob[rr][c4] = u;
  }

  // stage 1: msg3 = relu(msg2 @ W2^T + b2)
  {
    f32x4 acc[8] = {};
#pragma unroll
    for (int step = 0; step < 4; ++step) {
      const int k0 = step * 32 + kg * 8;
      f32x4 f1 = *(const f32x4*)(msg2 + (size_t)(wrow + r) * MDIM + k0);
      f32x4 f2 = *(const f32x4*)(msg2 + (size_t)(wrow + r) * MDIM + k0 + 4);
      s16x8 a = cvt8(f1, f2);
#pragma unroll
      for (int f = 0; f < 8; ++f) {
        const int col = f * 16 + r;
        s16x8 b = *(const s16x8*)(W2b + col * MDIM + k0);
        acc[f] = mfma16(a, b, acc[f]);
      }
    }
#pragma unroll
    for (int f = 0; f < 8; ++f) {
      const int col = f * 16 + r;
      const float bias = b2[col];
#pragma unroll
      for (int j = 0; j < 4; ++j) {
        const int rl = wave * 16 + kg * 4 + j;
        float v = acc[f][j] + bias;
        v = v > 0.f ? v : 0.f;
        msg3b[rl][col] = f2bf(v);
      }
    }
  }
  __syncthreads();

  // stage 2: gi = msg3 @ Wih^T + bih ; gh = mo @ Whh^T + bhh ; GRU combine
  f32x4 rreg[8], zreg[8];
#pragma unroll
  for (int chunk = 0; chunk < 3; ++chunk) {
    f32x4 gi[8] = {}, gh[8] = {};
#pragma unroll
    for (int step = 0; step < 4; ++step) {
      const int k0 = step * 32 + kg * 8;
      s16x8 ai = *(const s16x8*)&msg3b[wave * 16 + r][k0];
      s16x8 ah = *(const s16x8*)&mob[wave * 16 + r][k0];
#pragma unroll
      for (int f = 0; f < 8; ++f) {
        const int gn = chunk * 128 + f * 16 + r;
        s16x8 bi = *(const s16x8*)(Wihb + gn * MDIM + k0);
        s16x8 bh = *(const s16x8*)(Whhb + gn * MDIM + k0);
        gi[f] = mfma16(ai, bi, gi[f]);
        gh[f] = mfma16(ah, bh, gh[f]);
      }
    }
#pragma unroll
    for (int f = 0; f < 8; ++f) {
      const int gn = chunk * 128 + f * 16 + r;
      const float bi = bih[gn], bh = bhh[gn];
#pragma unroll
      for (int j = 0; j < 4; ++j) {
        const float giv = gi[f][j] + bi;
        const float ghv = gh[f][j] + bh;
        if (chunk == 0) {
          rreg[f][j] = sigmoidf_(giv + ghv);
        } else if (chunk == 1) {
          zreg[f][j] = sigmoidf_(giv + ghv);
        } else {
          const float n = tanhf(giv + rreg[f][j] * ghv);
          const int orow = row0 + wave * 16 + kg * 4 + j;
          const int col = f * 16 + r;
          const float m = mo[(size_t)orow * MDIM + col];
          const float z = zreg[f][j];
          out[(size_t)orow * MDIM + col] = (1.f - z) * n + z * m;
        }
      }
    }
  }
}

extern "C" void kernel_launch(void* const* d_in, const int* in_sizes, int n_in,
                              void* d_out, int out_size, void* d_ws, size_t ws_size,
                              hipStream_t stream) {
  const float* ef   = (const float*)d_in[0];
  const float* mo   = (const float*)d_in[1];
  const int*   arow = (const int*)d_in[2];
  const int*   acol = (const int*)d_in[3];
  const float* aval = (const float*)d_in[4];
  const float* W1   = (const float*)d_in[5];
  const float* b1   = (const float*)d_in[6];
  const float* W2   = (const float*)d_in[7];
  const float* b2   = (const float*)d_in[8];
  const float* Wih  = (const float*)d_in[9];
  const float* Whh  = (const float*)d_in[10];
  const float* bih  = (const float*)d_in[11];
  const float* bhh  = (const float*)d_in[12];
  float* out = (float*)d_out;

  const int E   = in_sizes[0] / EFDIM;   // 200000
  const int nnz = in_sizes[2];           // 1600000

  char* w = (char*)d_ws;
  size_t off = 0;
  ushort* msg1b = (ushort*)(w + off); off += (size_t)E * MDIM * 2;   // 51.2 MB
  float*  msg2  = (float*)(w + off);  off += (size_t)E * MDIM * 4;   // 102.4 MB
  ushort* W1b   = (ushort*)(w + off); off += 128 * K1PAD * 2;
  ushort* W2b   = (ushort*)(w + off); off += 128 * 128 * 2;
  ushort* Wihb  = (ushort*)(w + off); off += 384 * 128 * 2;
  ushort* Whhb  = (ushort*)(w + off); off += 384 * 128 * 2;
  if (off > ws_size) return;  // workspace too small (needs ~154 MB)

  const int prep_elems = 128 * K1PAD + 128 * 128 + 2 * 384 * 128;
  prep_kernel<<<(prep_elems + 255) / 256, 256, 0, stream>>>(W1, W2, Wih, Whh,
                                                            W1b, W2b, Wihb, Whhb);
  linear1_kernel<<<E / 64, 256, 0, stream>>>(mo, ef, W1b, b1, msg1b);
  hipMemsetAsync(msg2, 0, (size_t)E * MDIM * 4, stream);
  {
    const long long total = (long long)nnz * 32;
    const int grid = (int)((total + 255) / 256);
    spmm_kernel<<<grid, 256, 0, stream>>>(arow, acol, aval, msg1b, msg2, nnz);
  }
  gru_kernel<<<E / 64, 256, 0, stream>>>(msg2, mo, W2b, b2, Wihb, Whhb, bih, bhh, out);
}

// Round 2
// 854.780 us; speedup vs baseline: 3.7821x; 3.7821x over previous
//
#include <hip/hip_runtime.h>
#include <hip/hip_bf16.h>

// EdgeGNN layer: linear1(relu) -> SpMM (CSR counting-sort + gather) -> linear2(relu) -> GRUCell
// E=200000, NNZ=1600000, EF=16, M=128. bf16 MFMA for GEMMs; no f32 atomics.

typedef __attribute__((ext_vector_type(4))) float f32x4;
typedef __attribute__((ext_vector_type(8))) short s16x8;

#define MDIM 128
#define EFDIM 16
#define K1PAD 160   // 144 padded to 5*32
#define SCAN_BLK 1024  // elements per scan block (256 threads x 4)

__device__ __forceinline__ ushort f2bf(float f) {
  union { float f; unsigned u; } v; v.f = f;
  unsigned u = v.u;
  unsigned r = (u + 0x7fffu + ((u >> 16) & 1u)) >> 16;  // RNE
  return (ushort)r;
}
__device__ __forceinline__ float bf2f(ushort h) {
  union { unsigned u; float f; } v; v.u = ((unsigned)h) << 16; return v.f;
}
__device__ __forceinline__ s16x8 cvt8(f32x4 a, f32x4 b) {
  s16x8 o;
  o[0] = (short)f2bf(a[0]); o[1] = (short)f2bf(a[1]);
  o[2] = (short)f2bf(a[2]); o[3] = (short)f2bf(a[3]);
  o[4] = (short)f2bf(b[0]); o[5] = (short)f2bf(b[1]);
  o[6] = (short)f2bf(b[2]); o[7] = (short)f2bf(b[3]);
  return o;
}
__device__ __forceinline__ f32x4 mfma16(s16x8 a, s16x8 b, f32x4 c) {
  return __builtin_amdgcn_mfma_f32_16x16x32_bf16(a, b, c, 0, 0, 0);
}
__device__ __forceinline__ float sigmoidf_(float x) { return 1.f / (1.f + __expf(-x)); }

// ---------------- prep: bf16 weight conversion ----------------
__global__ __launch_bounds__(256) void prep_kernel(
    const float* __restrict__ W1, const float* __restrict__ W2,
    const float* __restrict__ Wih, const float* __restrict__ Whh,
    ushort* __restrict__ W1b, ushort* __restrict__ W2b,
    ushort* __restrict__ Wihb, ushort* __restrict__ Whhb) {
  int idx = blockIdx.x * 256 + threadIdx.x;
  if (idx < 128 * K1PAD) {
    int n = idx / K1PAD, k = idx % K1PAD;
    W1b[idx] = (k < 144) ? f2bf(W1[n * 144 + k]) : (ushort)0;
    return;
  }
  int i2 = idx - 128 * K1PAD;
  if (i2 < 128 * 128) { W2b[i2] = f2bf(W2[i2]); return; }
  int i3 = i2 - 128 * 128;
  if (i3 < 384 * 128) { Wihb[i3] = f2bf(Wih[i3]); return; }
  int i4 = i3 - 384 * 128;
  if (i4 < 384 * 128) { Whhb[i4] = f2bf(Whh[i4]); return; }
}

// ---------------- K1: msg1 = relu(concat(mo,ef) @ W1^T + b1), bf16 out ----------------
__global__ __launch_bounds__(256) void linear1_kernel(
    const float* __restrict__ mo, const float* __restrict__ ef,
    const ushort* __restrict__ W1b, const float* __restrict__ b1,
    ushort* __restrict__ msg1b) {
  const int tid = threadIdx.x;
  const int wave = tid >> 6, lane = tid & 63;
  const int r = lane & 15, kg = lane >> 4;
  const int row0 = blockIdx.x * 64 + wave * 16;
  const int arow = row0 + r;
  f32x4 acc[8] = {};
#pragma unroll
  for (int step = 0; step < 5; ++step) {
    const int k0 = step * 32 + kg * 8;
    s16x8 a;
    if (k0 < 128) {
      f32x4 f1 = *(const f32x4*)(mo + (size_t)arow * MDIM + k0);
      f32x4 f2 = *(const f32x4*)(mo + (size_t)arow * MDIM + k0 + 4);
      a = cvt8(f1, f2);
    } else if (k0 < 144) {
      f32x4 f1 = *(const f32x4*)(ef + (size_t)arow * EFDIM + (k0 - 128));
      f32x4 f2 = *(const f32x4*)(ef + (size_t)arow * EFDIM + (k0 - 128) + 4);
      a = cvt8(f1, f2);
    } else {
      a = (s16x8){0, 0, 0, 0, 0, 0, 0, 0};
    }
#pragma unroll
    for (int f = 0; f < 8; ++f) {
      const int col = f * 16 + r;
      s16x8 b = *(const s16x8*)(W1b + col * K1PAD + k0);
      acc[f] = mfma16(a, b, acc[f]);
    }
  }
#pragma unroll
  for (int f = 0; f < 8; ++f) {
    const int col = f * 16 + r;
    const float bias = b1[col];
#pragma unroll
    for (int j = 0; j < 4; ++j) {
      const int orow = row0 + kg * 4 + j;  // C/D layout: col=lane&15, row=(lane>>4)*4+j
      float v = acc[f][j] + bias;
      v = v > 0.f ? v : 0.f;
      msg1b[(size_t)orow * MDIM + col] = f2bf(v);
    }
  }
}

// ---------------- CSR build: histogram -> scan -> scatter ----------------
__global__ __launch_bounds__(256) void hist_kernel(const int* __restrict__ rows,
                                                   int* __restrict__ cnt, int nnz) {
  int i = blockIdx.x * 256 + threadIdx.x;
  if (i < nnz) atomicAdd(&cnt[rows[i]], 1);
}

// per-block exclusive scan; writes block-local exclusive prefixes + block sums
__global__ __launch_bounds__(256) void scan1_kernel(const int* __restrict__ cnt,
                                                    int* __restrict__ excl,
                                                    int* __restrict__ bsums, int n) {
  __shared__ int wsum[4];
  const int t = threadIdx.x;
  const int base = blockIdx.x * SCAN_BLK + t * 4;
  int v[4];
#pragma unroll
  for (int j = 0; j < 4; ++j) v[j] = (base + j < n) ? cnt[base + j] : 0;
  const int s = v[0] + v[1] + v[2] + v[3];
  const int lane = t & 63, wave = t >> 6;
  int inc = s;
#pragma unroll
  for (int d = 1; d < 64; d <<= 1) {
    int o = __shfl_up(inc, d, 64);
    if (lane >= d) inc += o;
  }
  if (lane == 63) wsum[wave] = inc;
  __syncthreads();
  int woff = 0;
#pragma unroll
  for (int wv = 0; wv < 4; ++wv) if (wv < wave) woff += wsum[wv];
  int run = woff + inc - s;  // exclusive prefix within block
#pragma unroll
  for (int j = 0; j < 4; ++j) {
    if (base + j < n) excl[base + j] = run;
    run += v[j];
  }
  if (t == 0) bsums[blockIdx.x] = wsum[0] + wsum[1] + wsum[2] + wsum[3];
}

// single-block exclusive scan of block sums (nb <= 256)
__global__ __launch_bounds__(256) void scan2_kernel(int* __restrict__ bsums, int nb) {
  __shared__ int ws[4];
  const int t = threadIdx.x;
  const int v = (t < nb) ? bsums[t] : 0;
  const int lane = t & 63, wave = t >> 6;
  int inc = v;
#pragma unroll
  for (int d = 1; d < 64; d <<= 1) {
    int o = __shfl_up(inc, d, 64);
    if (lane >= d) inc += o;
  }
  if (lane == 63) ws[wave] = inc;
  __syncthreads();
  int woff = 0;
#pragma unroll
  for (int wv = 0; wv < 4; ++wv) if (wv < wave) woff += ws[wv];
  if (t < nb) bsums[t] = woff + inc - v;
}

__global__ __launch_bounds__(256) void scan3_kernel(int* __restrict__ row_ptr,
                                                    int* __restrict__ row_fill,
                                                    const int* __restrict__ bsums, int n) {
  int i = blockIdx.x * 256 + threadIdx.x;
  if (i >= n) return;
  int v = row_ptr[i] + bsums[i / SCAN_BLK];
  row_ptr[i] = v;
  row_fill[i] = v;
}

__global__ __launch_bounds__(256) void scatter_kernel(
    const int* __restrict__ rows, const int* __restrict__ cols,
    const float* __restrict__ vals, int* __restrict__ row_fill,
    int2* __restrict__ csr, int nnz) {
  int i = blockIdx.x * 256 + threadIdx.x;
  if (i >= nnz) return;
  int r = rows[i];
  int idx = atomicAdd(&row_fill[r], 1);
  int2 cv;
  cv.x = cols[i];
  cv.y = __float_as_int(vals[i]);
  csr[idx] = cv;
}

// ---------------- gather SpMM: one wave per row, f32 accum, bf16 out ----------------
__global__ __launch_bounds__(256) void gather_kernel(
    const int* __restrict__ row_ptr, const int2* __restrict__ csr,
    const ushort* __restrict__ msg1b, ushort* __restrict__ msg2b,
    int E, int nnz) {
  const int w = (blockIdx.x * 256 + threadIdx.x) >> 6;  // one wave per row
  if (w >= E) return;
  const int lane = threadIdx.x & 63;
  const int start = row_ptr[w];
  const int end = (w == E - 1) ? nnz : row_ptr[w + 1];
  float a0 = 0.f, a1 = 0.f;
  for (int j = start; j < end; ++j) {
    const int2 cv = csr[j];
    const float val = __int_as_float(cv.y);
    const ushort2 m = *(const ushort2*)(msg1b + (size_t)cv.x * MDIM + lane * 2);
    a0 += bf2f(m.x) * val;
    a1 += bf2f(m.y) * val;
  }
  ushort2 o;
  o.x = f2bf(a0);
  o.y = f2bf(a1);
  *(ushort2*)(msg2b + (size_t)w * MDIM + lane * 2) = o;
}

// ---------------- K4: fused linear2(relu) + GRUCell ----------------
__global__ __launch_bounds__(256) void gru_kernel(
    const ushort* __restrict__ msg2b, const float* __restrict__ mo,
    const ushort* __restrict__ W2b, const float* __restrict__ b2,
    const ushort* __restrict__ Wihb, const ushort* __restrict__ Whhb,
    const float* __restrict__ bih, const float* __restrict__ bhh,
    float* __restrict__ out) {
  __shared__ ushort msg3b[64][MDIM + 8];
  __shared__ ushort mob[64][MDIM + 8];
  const int tid = threadIdx.x;
  const int wave = tid >> 6, lane = tid & 63;
  const int r = lane & 15, kg = lane >> 4;
  const int row0 = blockIdx.x * 64;
  const int wrow = row0 + wave * 16;

  // cooperative load of message_old tile -> bf16 LDS
#pragma unroll
  for (int it = 0; it < 8; ++it) {
    const int idx = it * 256 + tid;
    const int rr = idx >> 5, c4 = (idx & 31) * 4;
    f32x4 v = *(const f32x4*)(mo + (size_t)(row0 + rr) * MDIM + c4);
    ushort4 u;
    u.x = f2bf(v[0]); u.y = f2bf(v[1]); u.z = f2bf(v[2]); u.w = f2bf(v[3]);
    *(ushort4*)&mob[rr][c4] = u;
  }

  // stage 1: msg3 = relu(msg2 @ W2^T + b2)
  {
    f32x4 acc[8] = {};
#pragma unroll
    for (int step = 0; step < 4; ++step) {
      const int k0 = step * 32 + kg * 8;
      s16x8 a = *(const s16x8*)(msg2b + (size_t)(wrow + r) * MDIM + k0);
#pragma unroll
      for (int f = 0; f < 8; ++f) {
        const int col = f * 16 + r;
        s16x8 b = *(const s16x8*)(W2b + col * MDIM + k0);
        acc[f] = mfma16(a, b, acc[f]);
      }
    }
#pragma unroll
    for (int f = 0; f < 8; ++f) {
      const int col = f * 16 + r;
      const float bias = b2[col];
#pragma unroll
      for (int j = 0; j < 4; ++j) {
        const int rl = wave * 16 + kg * 4 + j;
        float v = acc[f][j] + bias;
        v = v > 0.f ? v : 0.f;
        msg3b[rl][col] = f2bf(v);
      }
    }
  }
  __syncthreads();

  // stage 2: gi = msg3 @ Wih^T + bih ; gh = mo @ Whh^T + bhh ; GRU combine
  f32x4 rreg[8], zreg[8];
#pragma unroll
  for (int chunk = 0; chunk < 3; ++chunk) {
    f32x4 gi[8] = {}, gh[8] = {};
#pragma unroll
    for (int step = 0; step < 4; ++step) {
      const int k0 = step * 32 + kg * 8;
      s16x8 ai = *(const s16x8*)&msg3b[wave * 16 + r][k0];
      s16x8 ah = *(const s16x8*)&mob[wave * 16 + r][k0];
#pragma unroll
      for (int f = 0; f < 8; ++f) {
        const int gn = chunk * 128 + f * 16 + r;
        s16x8 bi = *(const s16x8*)(Wihb + gn * MDIM + k0);
        s16x8 bh = *(const s16x8*)(Whhb + gn * MDIM + k0);
        gi[f] = mfma16(ai, bi, gi[f]);
        gh[f] = mfma16(ah, bh, gh[f]);
      }
    }
#pragma unroll
    for (int f = 0; f < 8; ++f) {
      const int gn = chunk * 128 + f * 16 + r;
      const float bi = bih[gn], bh = bhh[gn];
#pragma unroll
      for (int j = 0; j < 4; ++j) {
        const float giv = gi[f][j] + bi;
        const float ghv = gh[f][j] + bh;
        if (chunk == 0) {
          rreg[f][j] = sigmoidf_(giv + ghv);
        } else if (chunk == 1) {
          zreg[f][j] = sigmoidf_(giv + ghv);
        } else {
          const float n = tanhf(giv + rreg[f][j] * ghv);
          const int orow = row0 + wave * 16 + kg * 4 + j;
          const int col = f * 16 + r;
          const float m = mo[(size_t)orow * MDIM + col];
          const float z = zreg[f][j];
          out[(size_t)orow * MDIM + col] = (1.f - z) * n + z * m;
        }
      }
    }
  }
}

extern "C" void kernel_launch(void* const* d_in, const int* in_sizes, int n_in,
                              void* d_out, int out_size, void* d_ws, size_t ws_size,
                              hipStream_t stream) {
  const float* ef   = (const float*)d_in[0];
  const float* mo   = (const float*)d_in[1];
  const int*   arow = (const int*)d_in[2];
  const int*   acol = (const int*)d_in[3];
  const float* aval = (const float*)d_in[4];
  const float* W1   = (const float*)d_in[5];
  const float* b1   = (const float*)d_in[6];
  const float* W2   = (const float*)d_in[7];
  const float* b2   = (const float*)d_in[8];
  const float* Wih  = (const float*)d_in[9];
  const float* Whh  = (const float*)d_in[10];
  const float* bih  = (const float*)d_in[11];
  const float* bhh  = (const float*)d_in[12];
  float* out = (float*)d_out;

  const int E   = in_sizes[0] / EFDIM;   // 200000
  const int nnz = in_sizes[2];           // 1600000

  char* w = (char*)d_ws;
  size_t off = 0;
  ushort* msg1b   = (ushort*)(w + off); off += (size_t)E * MDIM * 2;   // 51.2 MB
  ushort* msg2b   = (ushort*)(w + off); off += (size_t)E * MDIM * 2;   // 51.2 MB
  int*    row_cnt = (int*)(w + off);    off += (size_t)E * 4;
  int*    row_ptr = (int*)(w + off);    off += (size_t)E * 4;
  int*    row_fill= (int*)(w + off);    off += (size_t)E * 4;
  int*    bsums   = (int*)(w + off);    off += 256 * 4;
  int2*   csr     = (int2*)(w + off);   off += (size_t)nnz * 8;        // 12.8 MB
  ushort* W1b     = (ushort*)(w + off); off += 128 * K1PAD * 2;
  ushort* W2b     = (ushort*)(w + off); off += 128 * 128 * 2;
  ushort* Wihb    = (ushort*)(w + off); off += 384 * 128 * 2;
  ushort* Whhb    = (ushort*)(w + off); off += 384 * 128 * 2;
  if (off > ws_size) return;  // needs ~118 MB

  const int prep_elems = 128 * K1PAD + 128 * 128 + 2 * 384 * 128;
  prep_kernel<<<(prep_elems + 255) / 256, 256, 0, stream>>>(W1, W2, Wih, Whh,
                                                            W1b, W2b, Wihb, Whhb);
  // linear1
  linear1_kernel<<<E / 64, 256, 0, stream>>>(mo, ef, W1b, b1, msg1b);

  // CSR build
  hipMemsetAsync(row_cnt, 0, (size_t)E * 4, stream);
  hist_kernel<<<(nnz + 255) / 256, 256, 0, stream>>>(arow, row_cnt, nnz);
  const int nscan = (E + SCAN_BLK - 1) / SCAN_BLK;  // 196 blocks
  scan1_kernel<<<nscan, 256, 0, stream>>>(row_cnt, row_ptr, bsums, E);
  scan2_kernel<<<1, 256, 0, stream>>>(bsums, nscan);
  scan3_kernel<<<(E + 255) / 256, 256, 0, stream>>>(row_ptr, row_fill, bsums, E);
  scatter_kernel<<<(nnz + 255) / 256, 256, 0, stream>>>(arow, acol, aval, row_fill, csr, nnz);

  // gather SpMM
  {
    const long long total = (long long)E * 64;
    const int grid = (int)((total + 255) / 256);
    gather_kernel<<<grid, 256, 0, stream>>>(row_ptr, csr, msg1b, msg2b, E, nnz);
  }

  // fused linear2 + GRU
  gru_kernel<<<E / 64, 256, 0, stream>>>(msg2b, mo, W2b, b2, Wihb, Whhb, bih, bhh, out);
}

// Round 3
// 777.098 us; speedup vs baseline: 4.1602x; 1.1000x over previous
//
#include <hip/hip_runtime.h>
#include <hip/hip_bf16.h>

// EdgeGNN layer: linear1(relu) -> SpMM (CSR counting-sort + gather) -> linear2(relu) -> GRUCell
// E=200000, NNZ=1600000, EF=16, M=128. bf16 MFMA for GEMMs; no f32 atomics.
// R2: gru_kernel restructured column-block-wise (6 accumulators, no r/z carry)
//     to cut VGPR 188->~128 and lift occupancy 2->4 waves/SIMD.

typedef __attribute__((ext_vector_type(4))) float f32x4;
typedef __attribute__((ext_vector_type(8))) short s16x8;

#define MDIM 128
#define EFDIM 16
#define K1PAD 160   // 144 padded to 5*32
#define SCAN_BLK 1024  // elements per scan block (256 threads x 4)

__device__ __forceinline__ ushort f2bf(float f) {
  union { float f; unsigned u; } v; v.f = f;
  unsigned u = v.u;
  unsigned r = (u + 0x7fffu + ((u >> 16) & 1u)) >> 16;  // RNE
  return (ushort)r;
}
__device__ __forceinline__ float bf2f(ushort h) {
  union { unsigned u; float f; } v; v.u = ((unsigned)h) << 16; return v.f;
}
__device__ __forceinline__ s16x8 cvt8(f32x4 a, f32x4 b) {
  s16x8 o;
  o[0] = (short)f2bf(a[0]); o[1] = (short)f2bf(a[1]);
  o[2] = (short)f2bf(a[2]); o[3] = (short)f2bf(a[3]);
  o[4] = (short)f2bf(b[0]); o[5] = (short)f2bf(b[1]);
  o[6] = (short)f2bf(b[2]); o[7] = (short)f2bf(b[3]);
  return o;
}
__device__ __forceinline__ f32x4 mfma16(s16x8 a, s16x8 b, f32x4 c) {
  return __builtin_amdgcn_mfma_f32_16x16x32_bf16(a, b, c, 0, 0, 0);
}
__device__ __forceinline__ float sigmoidf_(float x) { return 1.f / (1.f + __expf(-x)); }
__device__ __forceinline__ float tanhf_(float x) {
  float xc = fminf(fmaxf(x, -15.f), 15.f);
  float t = __expf(2.f * xc);
  return (t - 1.f) / (t + 1.f);
}

// ---------------- prep: bf16 weight conversion ----------------
__global__ __launch_bounds__(256) void prep_kernel(
    const float* __restrict__ W1, const float* __restrict__ W2,
    const float* __restrict__ Wih, const float* __restrict__ Whh,
    ushort* __restrict__ W1b, ushort* __restrict__ W2b,
    ushort* __restrict__ Wihb, ushort* __restrict__ Whhb) {
  int idx = blockIdx.x * 256 + threadIdx.x;
  if (idx < 128 * K1PAD) {
    int n = idx / K1PAD, k = idx % K1PAD;
    W1b[idx] = (k < 144) ? f2bf(W1[n * 144 + k]) : (ushort)0;
    return;
  }
  int i2 = idx - 128 * K1PAD;
  if (i2 < 128 * 128) { W2b[i2] = f2bf(W2[i2]); return; }
  int i3 = i2 - 128 * 128;
  if (i3 < 384 * 128) { Wihb[i3] = f2bf(Wih[i3]); return; }
  int i4 = i3 - 384 * 128;
  if (i4 < 384 * 128) { Whhb[i4] = f2bf(Whh[i4]); return; }
}

// ---------------- K1: msg1 = relu(concat(mo,ef) @ W1^T + b1), bf16 out ----------------
__global__ __launch_bounds__(256) void linear1_kernel(
    const float* __restrict__ mo, const float* __restrict__ ef,
    const ushort* __restrict__ W1b, const float* __restrict__ b1,
    ushort* __restrict__ msg1b) {
  const int tid = threadIdx.x;
  const int wave = tid >> 6, lane = tid & 63;
  const int r = lane & 15, kg = lane >> 4;
  const int row0 = blockIdx.x * 64 + wave * 16;
  const int arow = row0 + r;
  f32x4 acc[8] = {};
#pragma unroll
  for (int step = 0; step < 5; ++step) {
    const int k0 = step * 32 + kg * 8;
    s16x8 a;
    if (k0 < 128) {
      f32x4 f1 = *(const f32x4*)(mo + (size_t)arow * MDIM + k0);
      f32x4 f2 = *(const f32x4*)(mo + (size_t)arow * MDIM + k0 + 4);
      a = cvt8(f1, f2);
    } else if (k0 < 144) {
      f32x4 f1 = *(const f32x4*)(ef + (size_t)arow * EFDIM + (k0 - 128));
      f32x4 f2 = *(const f32x4*)(ef + (size_t)arow * EFDIM + (k0 - 128) + 4);
      a = cvt8(f1, f2);
    } else {
      a = (s16x8){0, 0, 0, 0, 0, 0, 0, 0};
    }
#pragma unroll
    for (int f = 0; f < 8; ++f) {
      const int col = f * 16 + r;
      s16x8 b = *(const s16x8*)(W1b + col * K1PAD + k0);
      acc[f] = mfma16(a, b, acc[f]);
    }
  }
#pragma unroll
  for (int f = 0; f < 8; ++f) {
    const int col = f * 16 + r;
    const float bias = b1[col];
#pragma unroll
    for (int j = 0; j < 4; ++j) {
      const int orow = row0 + kg * 4 + j;  // C/D layout: col=lane&15, row=(lane>>4)*4+j
      float v = acc[f][j] + bias;
      v = v > 0.f ? v : 0.f;
      msg1b[(size_t)orow * MDIM + col] = f2bf(v);
    }
  }
}

// ---------------- CSR build: histogram -> scan -> scatter ----------------
__global__ __launch_bounds__(256) void hist_kernel(const int* __restrict__ rows,
                                                   int* __restrict__ cnt, int nnz) {
  int i = blockIdx.x * 256 + threadIdx.x;
  if (i < nnz) atomicAdd(&cnt[rows[i]], 1);
}

__global__ __launch_bounds__(256) void scan1_kernel(const int* __restrict__ cnt,
                                                    int* __restrict__ excl,
                                                    int* __restrict__ bsums, int n) {
  __shared__ int wsum[4];
  const int t = threadIdx.x;
  const int base = blockIdx.x * SCAN_BLK + t * 4;
  int v[4];
#pragma unroll
  for (int j = 0; j < 4; ++j) v[j] = (base + j < n) ? cnt[base + j] : 0;
  const int s = v[0] + v[1] + v[2] + v[3];
  const int lane = t & 63, wave = t >> 6;
  int inc = s;
#pragma unroll
  for (int d = 1; d < 64; d <<= 1) {
    int o = __shfl_up(inc, d, 64);
    if (lane >= d) inc += o;
  }
  if (lane == 63) wsum[wave] = inc;
  __syncthreads();
  int woff = 0;
#pragma unroll
  for (int wv = 0; wv < 4; ++wv) if (wv < wave) woff += wsum[wv];
  int run = woff + inc - s;  // exclusive prefix within block
#pragma unroll
  for (int j = 0; j < 4; ++j) {
    if (base + j < n) excl[base + j] = run;
    run += v[j];
  }
  if (t == 0) bsums[blockIdx.x] = wsum[0] + wsum[1] + wsum[2] + wsum[3];
}

__global__ __launch_bounds__(256) void scan2_kernel(int* __restrict__ bsums, int nb) {
  __shared__ int ws[4];
  const int t = threadIdx.x;
  const int v = (t < nb) ? bsums[t] : 0;
  const int lane = t & 63, wave = t >> 6;
  int inc = v;
#pragma unroll
  for (int d = 1; d < 64; d <<= 1) {
    int o = __shfl_up(inc, d, 64);
    if (lane >= d) inc += o;
  }
  if (lane == 63) ws[wave] = inc;
  __syncthreads();
  int woff = 0;
#pragma unroll
  for (int wv = 0; wv < 4; ++wv) if (wv < wave) woff += ws[wv];
  if (t < nb) bsums[t] = woff + inc - v;
}

__global__ __launch_bounds__(256) void scan3_kernel(int* __restrict__ row_ptr,
                                                    int* __restrict__ row_fill,
                                                    const int* __restrict__ bsums, int n) {
  int i = blockIdx.x * 256 + threadIdx.x;
  if (i >= n) return;
  int v = row_ptr[i] + bsums[i / SCAN_BLK];
  row_ptr[i] = v;
  row_fill[i] = v;
}

__global__ __launch_bounds__(256) void scatter_kernel(
    const int* __restrict__ rows, const int* __restrict__ cols,
    const float* __restrict__ vals, int* __restrict__ row_fill,
    int2* __restrict__ csr, int nnz) {
  int i = blockIdx.x * 256 + threadIdx.x;
  if (i >= nnz) return;
  int r = rows[i];
  int idx = atomicAdd(&row_fill[r], 1);
  int2 cv;
  cv.x = cols[i];
  cv.y = __float_as_int(vals[i]);
  csr[idx] = cv;
}

// ---------------- gather SpMM: one wave per row, f32 accum, bf16 out ----------------
__global__ __launch_bounds__(256) void gather_kernel(
    const int* __restrict__ row_ptr, const int2* __restrict__ csr,
    const ushort* __restrict__ msg1b, ushort* __restrict__ msg2b,
    int E, int nnz) {
  const int w = (blockIdx.x * 256 + threadIdx.x) >> 6;  // one wave per row
  if (w >= E) return;
  const int lane = threadIdx.x & 63;
  const int start = row_ptr[w];
  const int end = (w == E - 1) ? nnz : row_ptr[w + 1];
  float a0 = 0.f, a1 = 0.f;
  for (int j = start; j < end; ++j) {
    const int2 cv = csr[j];
    const float val = __int_as_float(cv.y);
    const ushort2 m = *(const ushort2*)(msg1b + (size_t)cv.x * MDIM + lane * 2);
    a0 += bf2f(m.x) * val;
    a1 += bf2f(m.y) * val;
  }
  ushort2 o;
  o.x = f2bf(a0);
  o.y = f2bf(a1);
  *(ushort2*)(msg2b + (size_t)w * MDIM + lane * 2) = o;
}

// ---------------- K4: fused linear2(relu) + GRUCell ----------------
// 4 waves x 64 rows/block. Stage1: msg3 -> LDS bf16. Stage2: column-block-wise,
// 6 accumulators (i_r,h_r,i_z,h_z,i_n,h_n) per 16-col group, epilogue immediate.
__global__ __launch_bounds__(256, 4) void gru_kernel(
    const ushort* __restrict__ msg2b, const float* __restrict__ mo,
    const ushort* __restrict__ W2b, const float* __restrict__ b2,
    const ushort* __restrict__ Wihb, const ushort* __restrict__ Whhb,
    const float* __restrict__ bih, const float* __restrict__ bhh,
    float* __restrict__ out) {
  __shared__ ushort msg3b[64][MDIM + 8];
  __shared__ ushort mob[64][MDIM + 8];
  const int tid = threadIdx.x;
  const int wave = tid >> 6, lane = tid & 63;
  const int r = lane & 15, kg = lane >> 4;
  const int row0 = blockIdx.x * 64;
  const int wrow = row0 + wave * 16;

  // cooperative load of message_old tile -> bf16 LDS
#pragma unroll
  for (int it = 0; it < 8; ++it) {
    const int idx = it * 256 + tid;
    const int rr = idx >> 5, c4 = (idx & 31) * 4;
    f32x4 v = *(const f32x4*)(mo + (size_t)(row0 + rr) * MDIM + c4);
    ushort4 u;
    u.x = f2bf(v[0]); u.y = f2bf(v[1]); u.z = f2bf(v[2]); u.w = f2bf(v[3]);
    *(ushort4*)&mob[rr][c4] = u;
  }

  // stage 1: msg3 = relu(msg2 @ W2^T + b2)
  {
    f32x4 acc[8] = {};
#pragma unroll
    for (int step = 0; step < 4; ++step) {
      const int k0 = step * 32 + kg * 8;
      s16x8 a = *(const s16x8*)(msg2b + (size_t)(wrow + r) * MDIM + k0);
#pragma unroll
      for (int f = 0; f < 8; ++f) {
        const int col = f * 16 + r;
        s16x8 b = *(const s16x8*)(W2b + col * MDIM + k0);
        acc[f] = mfma16(a, b, acc[f]);
      }
    }
#pragma unroll
    for (int f = 0; f < 8; ++f) {
      const int col = f * 16 + r;
      const float bias = b2[col];
#pragma unroll
      for (int j = 0; j < 4; ++j) {
        const int rl = wave * 16 + kg * 4 + j;
        float v = acc[f][j] + bias;
        v = v > 0.f ? v : 0.f;
        msg3b[rl][col] = f2bf(v);
      }
    }
  }
  __syncthreads();

  // stage 2: hoist A-fragments once, then per 16-col group compute all six
  // gate partials and finish immediately (no carried r/z registers).
  s16x8 ai[4], ah[4];
#pragma unroll
  for (int step = 0; step < 4; ++step) {
    const int k0 = step * 32 + kg * 8;
    ai[step] = *(const s16x8*)&msg3b[wave * 16 + r][k0];
    ah[step] = *(const s16x8*)&mob[wave * 16 + r][k0];
  }

#pragma unroll
  for (int f = 0; f < 8; ++f) {
    const int col = f * 16 + r;
    const int cr = col, cz = 128 + col, cn = 256 + col;
    f32x4 a_ir = {}, a_hr = {}, a_iz = {}, a_hz = {}, a_in = {}, a_hn = {};
#pragma unroll
    for (int step = 0; step < 4; ++step) {
      const int k0 = step * 32 + kg * 8;
      s16x8 b_ir = *(const s16x8*)(Wihb + (size_t)cr * MDIM + k0);
      s16x8 b_hr = *(const s16x8*)(Whhb + (size_t)cr * MDIM + k0);
      a_ir = mfma16(ai[step], b_ir, a_ir);
      a_hr = mfma16(ah[step], b_hr, a_hr);
      s16x8 b_iz = *(const s16x8*)(Wihb + (size_t)cz * MDIM + k0);
      s16x8 b_hz = *(const s16x8*)(Whhb + (size_t)cz * MDIM + k0);
      a_iz = mfma16(ai[step], b_iz, a_iz);
      a_hz = mfma16(ah[step], b_hz, a_hz);
      s16x8 b_in = *(const s16x8*)(Wihb + (size_t)cn * MDIM + k0);
      s16x8 b_hn = *(const s16x8*)(Whhb + (size_t)cn * MDIM + k0);
      a_in = mfma16(ai[step], b_in, a_in);
      a_hn = mfma16(ah[step], b_hn, a_hn);
    }
    const float bi_r = bih[cr], bh_r = bhh[cr];
    const float bi_z = bih[cz], bh_z = bhh[cz];
    const float bi_n = bih[cn], bh_n = bhh[cn];
#pragma unroll
    for (int j = 0; j < 4; ++j) {
      const int rl = wave * 16 + kg * 4 + j;
      const float rr = sigmoidf_((a_ir[j] + bi_r) + (a_hr[j] + bh_r));
      const float zz = sigmoidf_((a_iz[j] + bi_z) + (a_hz[j] + bh_z));
      const float nn = tanhf_((a_in[j] + bi_n) + rr * (a_hn[j] + bh_n));
      const float m = bf2f(mob[rl][col]);
      out[(size_t)(row0 + rl) * MDIM + col] = (1.f - zz) * nn + zz * m;
    }
  }
}

extern "C" void kernel_launch(void* const* d_in, const int* in_sizes, int n_in,
                              void* d_out, int out_size, void* d_ws, size_t ws_size,
                              hipStream_t stream) {
  const float* ef   = (const float*)d_in[0];
  const float* mo   = (const float*)d_in[1];
  const int*   arow = (const int*)d_in[2];
  const int*   acol = (const int*)d_in[3];
  const float* aval = (const float*)d_in[4];
  const float* W1   = (const float*)d_in[5];
  const float* b1   = (const float*)d_in[6];
  const float* W2   = (const float*)d_in[7];
  const float* b2   = (const float*)d_in[8];
  const float* Wih  = (const float*)d_in[9];
  const float* Whh  = (const float*)d_in[10];
  const float* bih  = (const float*)d_in[11];
  const float* bhh  = (const float*)d_in[12];
  float* out = (float*)d_out;

  const int E   = in_sizes[0] / EFDIM;   // 200000
  const int nnz = in_sizes[2];           // 1600000

  char* w = (char*)d_ws;
  size_t off = 0;
  ushort* msg1b   = (ushort*)(w + off); off += (size_t)E * MDIM * 2;   // 51.2 MB
  ushort* msg2b   = (ushort*)(w + off); off += (size_t)E * MDIM * 2;   // 51.2 MB
  int*    row_cnt = (int*)(w + off);    off += (size_t)E * 4;
  int*    row_ptr = (int*)(w + off);    off += (size_t)E * 4;
  int*    row_fill= (int*)(w + off);    off += (size_t)E * 4;
  int*    bsums   = (int*)(w + off);    off += 256 * 4;
  int2*   csr     = (int2*)(w + off);   off += (size_t)nnz * 8;        // 12.8 MB
  ushort* W1b     = (ushort*)(w + off); off += 128 * K1PAD * 2;
  ushort* W2b     = (ushort*)(w + off); off += 128 * 128 * 2;
  ushort* Wihb    = (ushort*)(w + off); off += 384 * 128 * 2;
  ushort* Whhb    = (ushort*)(w + off); off += 384 * 128 * 2;
  if (off > ws_size) return;  // needs ~118 MB

  const int prep_elems = 128 * K1PAD + 128 * 128 + 2 * 384 * 128;
  prep_kernel<<<(prep_elems + 255) / 256, 256, 0, stream>>>(W1, W2, Wih, Whh,
                                                            W1b, W2b, Wihb, Whhb);
  // linear1
  linear1_kernel<<<E / 64, 256, 0, stream>>>(mo, ef, W1b, b1, msg1b);

  // CSR build
  hipMemsetAsync(row_cnt, 0, (size_t)E * 4, stream);
  hist_kernel<<<(nnz + 255) / 256, 256, 0, stream>>>(arow, row_cnt, nnz);
  const int nscan = (E + SCAN_BLK - 1) / SCAN_BLK;  // 196 blocks
  scan1_kernel<<<nscan, 256, 0, stream>>>(row_cnt, row_ptr, bsums, E);
  scan2_kernel<<<1, 256, 0, stream>>>(bsums, nscan);
  scan3_kernel<<<(E + 255) / 256, 256, 0, stream>>>(row_ptr, row_fill, bsums, E);
  scatter_kernel<<<(nnz + 255) / 256, 256, 0, stream>>>(arow, acol, aval, row_fill, csr, nnz);

  // gather SpMM
  {
    const long long total = (long long)E * 64;
    const int grid = (int)((total + 255) / 256);
    gather_kernel<<<grid, 256, 0, stream>>>(row_ptr, csr, msg1b, msg2b, E, nnz);
  }

  // fused linear2 + GRU
  gru_kernel<<<E / 64, 256, 0, stream>>>(msg2b, mo, W2b, b2, Wihb, Whhb, bih, bhh, out);
}

// Round 4
// 618.961 us; speedup vs baseline: 5.2230x; 1.2555x over previous
//
#include <hip/hip_runtime.h>
#include <hip/hip_bf16.h>

// EdgeGNN layer: linear1(relu) -> SpMM (CSR counting-sort + gather) -> linear2(relu) -> GRUCell
// E=200000, NNZ=1600000, EF=16, M=128. bf16 MFMA for GEMMs; no f32 atomics.
// R3: weights staged through XOR-swizzled LDS (write-late pipeline) in gru_kernel
//     and linear1_kernel — kills the global-B latency serialization seen in R2
//     (MfmaUtil 4.7%, all pipes idle).

typedef __attribute__((ext_vector_type(4))) float f32x4;
typedef __attribute__((ext_vector_type(8))) short s16x8;

#define MDIM 128
#define EFDIM 16
#define K1PAD 160   // 144 padded to 5*32
#define SCAN_BLK 1024

__device__ __forceinline__ ushort f2bf(float f) {
  union { float f; unsigned u; } v; v.f = f;
  unsigned u = v.u;
  unsigned r = (u + 0x7fffu + ((u >> 16) & 1u)) >> 16;  // RNE
  return (ushort)r;
}
__device__ __forceinline__ float bf2f(ushort h) {
  union { unsigned u; float f; } v; v.u = ((unsigned)h) << 16; return v.f;
}
__device__ __forceinline__ s16x8 cvt8(f32x4 a, f32x4 b) {
  s16x8 o;
  o[0] = (short)f2bf(a[0]); o[1] = (short)f2bf(a[1]);
  o[2] = (short)f2bf(a[2]); o[3] = (short)f2bf(a[3]);
  o[4] = (short)f2bf(b[0]); o[5] = (short)f2bf(b[1]);
  o[6] = (short)f2bf(b[2]); o[7] = (short)f2bf(b[3]);
  return o;
}
__device__ __forceinline__ f32x4 mfma16(s16x8 a, s16x8 b, f32x4 c) {
  return __builtin_amdgcn_mfma_f32_16x16x32_bf16(a, b, c, 0, 0, 0);
}
__device__ __forceinline__ float sigmoidf_(float x) { return 1.f / (1.f + __expf(-x)); }
__device__ __forceinline__ float tanhf_(float x) {
  float xc = fminf(fmaxf(x, -15.f), 15.f);
  float t = __expf(2.f * xc);
  return (t - 1.f) / (t + 1.f);
}

// ---------------- prep: bf16 weight conversion ----------------
__global__ __launch_bounds__(256) void prep_kernel(
    const float* __restrict__ W1, const float* __restrict__ W2,
    const float* __restrict__ Wih, const float* __restrict__ Whh,
    ushort* __restrict__ W1b, ushort* __restrict__ W2b,
    ushort* __restrict__ Wihb, ushort* __restrict__ Whhb) {
  int idx = blockIdx.x * 256 + threadIdx.x;
  if (idx < 128 * K1PAD) {
    int n = idx / K1PAD, k = idx % K1PAD;
    W1b[idx] = (k < 144) ? f2bf(W1[n * 144 + k]) : (ushort)0;
    return;
  }
  int i2 = idx - 128 * K1PAD;
  if (i2 < 128 * 128) { W2b[i2] = f2bf(W2[i2]); return; }
  int i3 = i2 - 128 * 128;
  if (i3 < 384 * 128) { Wihb[i3] = f2bf(Wih[i3]); return; }
  int i4 = i3 - 384 * 128;
  if (i4 < 384 * 128) { Whhb[i4] = f2bf(Whh[i4]); return; }
}

// ---------------- K1: msg1 = relu(concat(mo,ef) @ W1^T + b1), bf16 out ----------------
// W1 staged in swizzled LDS: row stride 192 ushort (384B, bank-aligned), granule
// (8 ushort) index g stored at g ^ (row&7)  -> 2-way banks on ds_read_b128 (free).
__global__ __launch_bounds__(256) void linear1_kernel(
    const float* __restrict__ mo, const float* __restrict__ ef,
    const ushort* __restrict__ W1b, const float* __restrict__ b1,
    ushort* __restrict__ msg1b) {
  __shared__ ushort w1l[128 * 192];  // 48KB
  const int tid = threadIdx.x;
  const int wave = tid >> 6, lane = tid & 63;
  const int r = lane & 15, kg = lane >> 4;
  const int row0 = blockIdx.x * 64 + wave * 16;
  const int arow = row0 + r;

  // cooperative stage: 128 rows x 20 granules = 2560 granules, 10 per thread
#pragma unroll
  for (int l = 0; l < 10; ++l) {
    const int gid = l * 256 + tid;
    const int row = gid / 20, g = gid - row * 20;
    uint4 v = *(const uint4*)(W1b + row * K1PAD + g * 8);
    *(uint4*)&w1l[row * 192 + ((g ^ (row & 7)) * 8)] = v;
  }
  __syncthreads();

  f32x4 acc[8] = {};
#pragma unroll
  for (int step = 0; step < 5; ++step) {
    const int k0 = step * 32 + kg * 8;
    s16x8 a;
    if (k0 < 128) {
      f32x4 f1 = *(const f32x4*)(mo + (size_t)arow * MDIM + k0);
      f32x4 f2 = *(const f32x4*)(mo + (size_t)arow * MDIM + k0 + 4);
      a = cvt8(f1, f2);
    } else if (k0 < 144) {
      f32x4 f1 = *(const f32x4*)(ef + (size_t)arow * EFDIM + (k0 - 128));
      f32x4 f2 = *(const f32x4*)(ef + (size_t)arow * EFDIM + (k0 - 128) + 4);
      a = cvt8(f1, f2);
    } else {
      a = (s16x8){0, 0, 0, 0, 0, 0, 0, 0};
    }
#pragma unroll
    for (int f = 0; f < 8; ++f) {
      const int col = f * 16 + r;
      s16x8 b = *(const s16x8*)&w1l[col * 192 + (((step * 4 + kg) ^ (col & 7)) * 8)];
      acc[f] = mfma16(a, b, acc[f]);
    }
  }
#pragma unroll
  for (int f = 0; f < 8; ++f) {
    const int col = f * 16 + r;
    const float bias = b1[col];
#pragma unroll
    for (int j = 0; j < 4; ++j) {
      const int orow = row0 + kg * 4 + j;  // C/D layout: col=lane&15, row=(lane>>4)*4+j
      float v = acc[f][j] + bias;
      v = v > 0.f ? v : 0.f;
      msg1b[(size_t)orow * MDIM + col] = f2bf(v);
    }
  }
}

// ---------------- CSR build: histogram -> scan -> scatter ----------------
__global__ __launch_bounds__(256) void hist_kernel(const int* __restrict__ rows,
                                                   int* __restrict__ cnt, int nnz) {
  int i = blockIdx.x * 256 + threadIdx.x;
  if (i < nnz) atomicAdd(&cnt[rows[i]], 1);
}

__global__ __launch_bounds__(256) void scan1_kernel(const int* __restrict__ cnt,
                                                    int* __restrict__ excl,
                                                    int* __restrict__ bsums, int n) {
  __shared__ int wsum[4];
  const int t = threadIdx.x;
  const int base = blockIdx.x * SCAN_BLK + t * 4;
  int v[4];
#pragma unroll
  for (int j = 0; j < 4; ++j) v[j] = (base + j < n) ? cnt[base + j] : 0;
  const int s = v[0] + v[1] + v[2] + v[3];
  const int lane = t & 63, wave = t >> 6;
  int inc = s;
#pragma unroll
  for (int d = 1; d < 64; d <<= 1) {
    int o = __shfl_up(inc, d, 64);
    if (lane >= d) inc += o;
  }
  if (lane == 63) wsum[wave] = inc;
  __syncthreads();
  int woff = 0;
#pragma unroll
  for (int wv = 0; wv < 4; ++wv) if (wv < wave) woff += wsum[wv];
  int run = woff + inc - s;
#pragma unroll
  for (int j = 0; j < 4; ++j) {
    if (base + j < n) excl[base + j] = run;
    run += v[j];
  }
  if (t == 0) bsums[blockIdx.x] = wsum[0] + wsum[1] + wsum[2] + wsum[3];
}

__global__ __launch_bounds__(256) void scan2_kernel(int* __restrict__ bsums, int nb) {
  __shared__ int ws[4];
  const int t = threadIdx.x;
  const int v = (t < nb) ? bsums[t] : 0;
  const int lane = t & 63, wave = t >> 6;
  int inc = v;
#pragma unroll
  for (int d = 1; d < 64; d <<= 1) {
    int o = __shfl_up(inc, d, 64);
    if (lane >= d) inc += o;
  }
  if (lane == 63) ws[wave] = inc;
  __syncthreads();
  int woff = 0;
#pragma unroll
  for (int wv = 0; wv < 4; ++wv) if (wv < wave) woff += ws[wv];
  if (t < nb) bsums[t] = woff + inc - v;
}

__global__ __launch_bounds__(256) void scan3_kernel(int* __restrict__ row_ptr,
                                                    int* __restrict__ row_fill,
                                                    const int* __restrict__ bsums, int n) {
  int i = blockIdx.x * 256 + threadIdx.x;
  if (i >= n) return;
  int v = row_ptr[i] + bsums[i / SCAN_BLK];
  row_ptr[i] = v;
  row_fill[i] = v;
}

__global__ __launch_bounds__(256) void scatter_kernel(
    const int* __restrict__ rows, const int* __restrict__ cols,
    const float* __restrict__ vals, int* __restrict__ row_fill,
    int2* __restrict__ csr, int nnz) {
  int i = blockIdx.x * 256 + threadIdx.x;
  if (i >= nnz) return;
  int r = rows[i];
  int idx = atomicAdd(&row_fill[r], 1);
  int2 cv;
  cv.x = cols[i];
  cv.y = __float_as_int(vals[i]);
  csr[idx] = cv;
}

// ---------------- gather SpMM: one wave per row, f32 accum, bf16 out ----------------
__global__ __launch_bounds__(256) void gather_kernel(
    const int* __restrict__ row_ptr, const int2* __restrict__ csr,
    const ushort* __restrict__ msg1b, ushort* __restrict__ msg2b,
    int E, int nnz) {
  const int w = (blockIdx.x * 256 + threadIdx.x) >> 6;
  if (w >= E) return;
  const int lane = threadIdx.x & 63;
  const int start = row_ptr[w];
  const int end = (w == E - 1) ? nnz : row_ptr[w + 1];
  float a0 = 0.f, a1 = 0.f;
  for (int j = start; j < end; ++j) {
    const int2 cv = csr[j];
    const float val = __int_as_float(cv.y);
    const ushort2 m = *(const ushort2*)(msg1b + (size_t)cv.x * MDIM + lane * 2);
    a0 += bf2f(m.x) * val;
    a1 += bf2f(m.y) * val;
  }
  ushort2 o;
  o.x = f2bf(a0);
  o.y = f2bf(a1);
  *(ushort2*)(msg2b + (size_t)w * MDIM + lane * 2) = o;
}

// ---------------- K4: fused linear2(relu) + GRUCell ----------------
// 24KB LDS pool, time-multiplexed with XOR granule swizzle (g ^= row&7):
//  phase 0: mo tile -> buf[64][128]; hoist ah (A-frags) + packed mo epilogue vals.
//  phase 1: stage1 GEMM, W2 double-buffered in 2x4KB tiles; msg3 -> buf; hoist ai.
//  phase 2: 8 unrolled phases; per phase stage 6x16x128 Wih/Whh tiles (write-late),
//           24 ds_read_b128 + 24 MFMA + transcendental epilogue + coalesced-ish out.
__global__ __launch_bounds__(256) void gru_kernel(
    const ushort* __restrict__ msg2b, const float* __restrict__ mo,
    const ushort* __restrict__ W2b, const float* __restrict__ b2,
    const ushort* __restrict__ Wihb, const ushort* __restrict__ Whhb,
    const float* __restrict__ bih, const float* __restrict__ bhh,
    float* __restrict__ out) {
  __shared__ ushort lds[12288];  // 24KB: buf=[0,8192), w2 slots=[8192,12288); wt=[0,12288)
  const int tid = threadIdx.x;
  const int wave = tid >> 6, lane = tid & 63;
  const int r = lane & 15, kg = lane >> 4;
  const int row0 = blockIdx.x * 64;
  const int wrow = row0 + wave * 16;
  const int rid = tid >> 4, gg = tid & 15;  // staging coords

  // ---- phase 0: mo -> buf (bf16, swizzled) ----
#pragma unroll
  for (int it = 0; it < 8; ++it) {
    const int idx = it * 256 + tid;
    const int rr = idx >> 5, c4 = (idx & 31) * 4;
    f32x4 v = *(const f32x4*)(mo + (size_t)(row0 + rr) * MDIM + c4);
    ushort4 u;
    u.x = f2bf(v[0]); u.y = f2bf(v[1]); u.z = f2bf(v[2]); u.w = f2bf(v[3]);
    *(ushort4*)&lds[rr * 128 + (c4 ^ ((rr & 7) << 3))] = u;
  }
  __syncthreads();

  // hoist ah (A-fragments of message_old) + packed mo epilogue values
  s16x8 ah[4];
#pragma unroll
  for (int step = 0; step < 4; ++step) {
    const int row = wave * 16 + r, k0 = step * 32 + kg * 8;
    ah[step] = *(const s16x8*)&lds[row * 128 + (k0 ^ ((row & 7) << 3))];
  }
  uint mo_pk[16];
#pragma unroll
  for (int f = 0; f < 8; ++f) {
#pragma unroll
    for (int jj = 0; jj < 2; ++jj) {
      const int rl0 = wave * 16 + kg * 4 + jj * 2;
      const int col = f * 16 + r;
      ushort u0 = lds[rl0 * 128 + (col ^ ((rl0 & 7) << 3))];
      ushort u1 = lds[(rl0 + 1) * 128 + (col ^ (((rl0 + 1) & 7) << 3))];
      mo_pk[f * 2 + jj] = (uint)u0 | ((uint)u1 << 16);
    }
  }

  // ---- phase 1: stage1 GEMM (msg3 = relu(msg2 @ W2^T + b2)) -> buf ----
  s16x8 a1[4];
#pragma unroll
  for (int step = 0; step < 4; ++step)
    a1[step] = *(const s16x8*)(msg2b + (size_t)(wrow + r) * MDIM + step * 32 + kg * 8);

  {
    uint4 w2reg = *(const uint4*)(W2b + (size_t)rid * 128 + gg * 8);  // f=0 tile
    *(uint4*)&lds[8192 + rid * 128 + ((gg * 8) ^ ((rid & 7) << 3))] = w2reg;
#pragma unroll
    for (int f = 0; f < 8; ++f) {
      if (f < 7)
        w2reg = *(const uint4*)(W2b + (size_t)((f + 1) * 16 + rid) * 128 + gg * 8);
      __syncthreads();
      f32x4 acc = {};
#pragma unroll
      for (int step = 0; step < 4; ++step) {
        const int k0 = step * 32 + kg * 8;
        s16x8 b = *(const s16x8*)&lds[8192 + (f & 1) * 2048 + r * 128 + (k0 ^ ((r & 7) << 3))];
        acc = mfma16(a1[step], b, acc);
      }
      const int col = f * 16 + r;
      const float bias = b2[col];
#pragma unroll
      for (int j = 0; j < 4; ++j) {
        const int rl = wave * 16 + kg * 4 + j;
        float v = acc[j] + bias;
        v = v > 0.f ? v : 0.f;
        lds[rl * 128 + (col ^ ((rl & 7) << 3))] = f2bf(v);
      }
      if (f < 7)
        *(uint4*)&lds[8192 + ((f + 1) & 1) * 2048 + rid * 128 + ((gg * 8) ^ ((rid & 7) << 3))] = w2reg;
    }
  }

  // hoist ai (A-fragments of msg3; own-wave rows, RAW via lgkmcnt)
  s16x8 ai[4];
#pragma unroll
  for (int step = 0; step < 4; ++step) {
    const int row = wave * 16 + r, k0 = step * 32 + kg * 8;
    ai[step] = *(const s16x8*)&lds[row * 128 + (k0 ^ ((row & 7) << 3))];
  }
  __syncthreads();  // all reads of buf/w2 slots done before wt overwrites

  // ---- phase 2: gate GEMMs with 6-section weight tiles, write-late staging ----
  // wt[sec][16][128] at lds + sec*2048; sec: 0=Wih.r 1=Whh.r 2=Wih.z 3=Whh.z 4=Wih.n 5=Whh.n
  uint4 wreg[6];
#pragma unroll
  for (int l = 0; l < 6; ++l) {
    const ushort* src = (l & 1) ? Whhb : Wihb;
    const int gate = l >> 1;
    wreg[l] = *(const uint4*)(src + (size_t)(gate * 128 + rid) * 128 + gg * 8);
  }
#pragma unroll
  for (int l = 0; l < 6; ++l)
    *(uint4*)&lds[l * 2048 + rid * 128 + ((gg * 8) ^ ((rid & 7) << 3))] = wreg[l];

#pragma unroll
  for (int f = 0; f < 8; ++f) {
    if (f < 7) {
#pragma unroll
      for (int l = 0; l < 6; ++l) {
        const ushort* src = (l & 1) ? Whhb : Wihb;
        const int gate = l >> 1;
        wreg[l] = *(const uint4*)(src + (size_t)(gate * 128 + (f + 1) * 16 + rid) * 128 + gg * 8);
      }
    }
    __syncthreads();  // wt[f] visible
    f32x4 a_ir = {}, a_hr = {}, a_iz = {}, a_hz = {}, a_in = {}, a_hn = {};
#pragma unroll
    for (int step = 0; step < 4; ++step) {
      const int k0 = step * 32 + kg * 8;
      const int sw = (k0 ^ ((r & 7) << 3)) + r * 128;
      s16x8 b_ir = *(const s16x8*)&lds[0 * 2048 + sw];
      s16x8 b_hr = *(const s16x8*)&lds[1 * 2048 + sw];
      a_ir = mfma16(ai[step], b_ir, a_ir);
      a_hr = mfma16(ah[step], b_hr, a_hr);
      s16x8 b_iz = *(const s16x8*)&lds[2 * 2048 + sw];
      s16x8 b_hz = *(const s16x8*)&lds[3 * 2048 + sw];
      a_iz = mfma16(ai[step], b_iz, a_iz);
      a_hz = mfma16(ah[step], b_hz, a_hz);
      s16x8 b_in = *(const s16x8*)&lds[4 * 2048 + sw];
      s16x8 b_hn = *(const s16x8*)&lds[5 * 2048 + sw];
      a_in = mfma16(ai[step], b_in, a_in);
      a_hn = mfma16(ah[step], b_hn, a_hn);
    }
    const int cr = f * 16 + r, cz = 128 + cr, cn = 256 + cr;
    const float bi_r = bih[cr], bh_r = bhh[cr];
    const float bi_z = bih[cz], bh_z = bhh[cz];
    const float bi_n = bih[cn], bh_n = bhh[cn];
#pragma unroll
    for (int j = 0; j < 4; ++j) {
      const int rl = wave * 16 + kg * 4 + j;
      const float rr_ = sigmoidf_((a_ir[j] + bi_r) + (a_hr[j] + bh_r));
      const float zz = sigmoidf_((a_iz[j] + bi_z) + (a_hz[j] + bh_z));
      const float nn = tanhf_((a_in[j] + bi_n) + rr_ * (a_hn[j] + bh_n));
      const uint pk = mo_pk[f * 2 + (j >> 1)];
      const float m = bf2f((ushort)((j & 1) ? (pk >> 16) : (pk & 0xffffu)));
      out[(size_t)(row0 + rl) * MDIM + cr] = (1.f - zz) * nn + zz * m;
    }
    __syncthreads();  // all reads of wt[f] done
    if (f < 7) {
#pragma unroll
      for (int l = 0; l < 6; ++l)
        *(uint4*)&lds[l * 2048 + rid * 128 + ((gg * 8) ^ ((rid & 7) << 3))] = wreg[l];
    }
  }
}

extern "C" void kernel_launch(void* const* d_in, const int* in_sizes, int n_in,
                              void* d_out, int out_size, void* d_ws, size_t ws_size,
                              hipStream_t stream) {
  const float* ef   = (const float*)d_in[0];
  const float* mo   = (const float*)d_in[1];
  const int*   arow = (const int*)d_in[2];
  const int*   acol = (const int*)d_in[3];
  const float* aval = (const float*)d_in[4];
  const float* W1   = (const float*)d_in[5];
  const float* b1   = (const float*)d_in[6];
  const float* W2   = (const float*)d_in[7];
  const float* b2   = (const float*)d_in[8];
  const float* Wih  = (const float*)d_in[9];
  const float* Whh  = (const float*)d_in[10];
  const float* bih  = (const float*)d_in[11];
  const float* bhh  = (const float*)d_in[12];
  float* out = (float*)d_out;

  const int E   = in_sizes[0] / EFDIM;   // 200000
  const int nnz = in_sizes[2];           // 1600000

  char* w = (char*)d_ws;
  size_t off = 0;
  ushort* msg1b   = (ushort*)(w + off); off += (size_t)E * MDIM * 2;   // 51.2 MB
  ushort* msg2b   = (ushort*)(w + off); off += (size_t)E * MDIM * 2;   // 51.2 MB
  int*    row_cnt = (int*)(w + off);    off += (size_t)E * 4;
  int*    row_ptr = (int*)(w + off);    off += (size_t)E * 4;
  int*    row_fill= (int*)(w + off);    off += (size_t)E * 4;
  int*    bsums   = (int*)(w + off);    off += 256 * 4;
  int2*   csr     = (int2*)(w + off);   off += (size_t)nnz * 8;        // 12.8 MB
  ushort* W1b     = (ushort*)(w + off); off += 128 * K1PAD * 2;
  ushort* W2b     = (ushort*)(w + off); off += 128 * 128 * 2;
  ushort* Wihb    = (ushort*)(w + off); off += 384 * 128 * 2;
  ushort* Whhb    = (ushort*)(w + off); off += 384 * 128 * 2;
  if (off > ws_size) return;  // needs ~118 MB

  const int prep_elems = 128 * K1PAD + 128 * 128 + 2 * 384 * 128;
  prep_kernel<<<(prep_elems + 255) / 256, 256, 0, stream>>>(W1, W2, Wih, Whh,
                                                            W1b, W2b, Wihb, Whhb);
  // linear1
  linear1_kernel<<<E / 64, 256, 0, stream>>>(mo, ef, W1b, b1, msg1b);

  // CSR build
  hipMemsetAsync(row_cnt, 0, (size_t)E * 4, stream);
  hist_kernel<<<(nnz + 255) / 256, 256, 0, stream>>>(arow, row_cnt, nnz);
  const int nscan = (E + SCAN_BLK - 1) / SCAN_BLK;  // 196 blocks
  scan1_kernel<<<nscan, 256, 0, stream>>>(row_cnt, row_ptr, bsums, E);
  scan2_kernel<<<1, 256, 0, stream>>>(bsums, nscan);
  scan3_kernel<<<(E + 255) / 256, 256, 0, stream>>>(row_ptr, row_fill, bsums, E);
  scatter_kernel<<<(nnz + 255) / 256, 256, 0, stream>>>(arow, acol, aval, row_fill, csr, nnz);

  // gather SpMM
  {
    const long long total = (long long)E * 64;
    const int grid = (int)((total + 255) / 256);
    gather_kernel<<<grid, 256, 0, stream>>>(row_ptr, csr, msg1b, msg2b, E, nnz);
  }

  // fused linear2 + GRU
  gru_kernel<<<E / 64, 256, 0, stream>>>(msg2b, mo, W2b, b2, Wihb, Whhb, bih, bhh, out);
}